// Round 2
// baseline (905.751 us; speedup 1.0000x reference)
//
#include <hip/hip_runtime.h>
#include <math.h>

#define KCODES 512
#define CDIM   64
#define HWPIX  4096      // 64*64
#define BATCH  32
#define NPIX   (BATCH * HWPIX)   // 131072
#define COMMIT 0.25f
#define TAU    2e-3f     // fp32 distance error bound (~1e-4) x safety margin

// ws layout (floats):
//   [0 .. 511]      e2[k]        = ||embedding_k||^2
//   [512 .. 1023]   counts[k]    (as unsigned)
//   [1024 .. 1535]  blockloss[b] per-block partial loss sums
__global__ void vq_prep(const float* __restrict__ emb, float* __restrict__ ws) {
    int k = threadIdx.x;
    if (k < KCODES) {
        const float* e = emb + k * CDIM;
        double s = 0.0;
#pragma unroll
        for (int c = 0; c < CDIM; ++c) s += (double)e[c] * (double)e[c];
        ws[k] = (float)s;
        ((unsigned*)ws)[KCODES + k] = 0u;
    }
}

__launch_bounds__(256)
__global__ void vq_main(const float* __restrict__ in, const float* __restrict__ emb,
                        float* __restrict__ ws, float* __restrict__ out) {
    __shared__ unsigned hist[KCODES];
    __shared__ float wsum[4];

    for (int i = threadIdx.x; i < KCODES; i += 256) hist[i] = 0u;

    int n  = blockIdx.x * 256 + threadIdx.x;   // pixel id
    int b  = n >> 12;                          // n / 4096
    int hw = n & 4095;
    const float* xp = in + (size_t)b * CDIM * HWPIX + hw;

    float x[CDIM];
#pragma unroll
    for (int c = 0; c < CDIM; ++c) x[c] = xp[c * HWPIX];

    float x2 = 0.f;
#pragma unroll
    for (int c = 0; c < CDIM; ++c) x2 += x[c] * x[c];

    const float* __restrict__ e2 = ws;
    float bestd  = 1e30f;   // best  (d = ||e||^2 - 2 x.e ; ||x||^2 dropped)
    float bestd2 = 1e30f;   // second best
    int   besti  = 0;
    for (int k = 0; k < KCODES; ++k) {
        const float* e = emb + k * CDIM;       // wave-uniform address
        float d0 = 0.f, d1 = 0.f, d2 = 0.f, d3 = 0.f;
#pragma unroll
        for (int c = 0; c < CDIM; c += 4) {
            d0 += x[c + 0] * e[c + 0];
            d1 += x[c + 1] * e[c + 1];
            d2 += x[c + 2] * e[c + 2];
            d3 += x[c + 3] * e[c + 3];
        }
        float dot = (d0 + d1) + (d2 + d3);
        float d = e2[k] - 2.f * dot;
        if (d < bestd)       { bestd2 = bestd; bestd = d; besti = k; }
        else if (d < bestd2) { bestd2 = d; }
    }

    float lossv;
    if (bestd2 - bestd <= TAU) {
        // near-tie: resolve exactly in fp64 (rare — ~1e-4 of pixels)
        double bd = 1e300;
        int    bi = 0;
        for (int k = 0; k < KCODES; ++k) {
            const float* e = emb + k * CDIM;
            double s0 = 0.0, s1 = 0.0;
#pragma unroll
            for (int c = 0; c < CDIM; c += 2) {
                double t0 = (double)x[c]     - (double)e[c];
                double t1 = (double)x[c + 1] - (double)e[c + 1];
                s0 += t0 * t0;
                s1 += t1 * t1;
            }
            double dk = s0 + s1;
            if (dk < bd) { bd = dk; bi = k; }   // strict <: lowest index wins ties
        }
        besti = bi;
        lossv = (float)bd;
    } else {
        lossv = x2 + bestd;                    // ||x - e_best||^2
    }

    out[2 + n] = (float)besti;

#pragma unroll
    for (int off = 32; off > 0; off >>= 1) lossv += __shfl_down(lossv, off, 64);
    int wave = threadIdx.x >> 6;
    int lane = threadIdx.x & 63;
    if (lane == 0) wsum[wave] = lossv;

    __syncthreads();   // covers: hist zero done, wsum written

    if (threadIdx.x == 0) {
        float s = (wsum[0] + wsum[1]) + (wsum[2] + wsum[3]);
        ws[2 * KCODES + blockIdx.x] = s;
    }

    atomicAdd(&hist[besti], 1u);
    __syncthreads();

    unsigned* counts = ((unsigned*)ws) + KCODES;
    for (int i = threadIdx.x; i < KCODES; i += 256) {
        unsigned v = hist[i];
        if (v) atomicAdd(&counts[i], v);
    }
}

__global__ void vq_final(const float* __restrict__ ws, float* __restrict__ out) {
    __shared__ float red[KCODES];
    int t = threadIdx.x;

    red[t] = ws[2 * KCODES + t];
    __syncthreads();
    for (int s = 256; s > 0; s >>= 1) {
        if (t < s) red[t] += red[t + s];
        __syncthreads();
    }
    float loss_sum = red[0];
    __syncthreads();

    unsigned cnt = ((const unsigned*)ws)[KCODES + t];
    float p = (float)cnt / (float)NPIX;
    red[t] = p * logf(p + 1e-10f);
    __syncthreads();
    for (int s = 256; s > 0; s >>= 1) {
        if (t < s) red[t] += red[t + s];
        __syncthreads();
    }
    if (t == 0) {
        out[0] = COMMIT * loss_sum / (float)(NPIX * (size_t)CDIM);
        out[1] = expf(-red[0]);
    }
}

extern "C" void kernel_launch(void* const* d_in, const int* in_sizes, int n_in,
                              void* d_out, int out_size, void* d_ws, size_t ws_size,
                              hipStream_t stream) {
    const float* in  = (const float*)d_in[0];   // [32, 64, 64, 64] f32
    const float* emb = (const float*)d_in[1];   // [512, 64] f32
    float* out = (float*)d_out;                 // [1 + 1 + 131072] f32
    float* ws  = (float*)d_ws;

    vq_prep<<<1, KCODES, 0, stream>>>(emb, ws);
    vq_main<<<NPIX / 256, 256, 0, stream>>>(in, emb, ws, out);
    vq_final<<<1, KCODES, 0, stream>>>(ws, out);
}

// Round 3
// 272.237 us; speedup vs baseline: 3.3271x; 3.3271x over previous
//
#include <hip/hip_runtime.h>
#include <math.h>

#define KCODES 512
#define CDIM   64
#define HWPIX  4096
#define NPIX   131072
#define BN     128            // pixels per block
#define BKC    64             // codes per K-chunk
#define NCHUNK (KCODES / BKC) // 8
#define COMMIT 0.25f
#define TAU    2e-3f
#define ESTRIDE 68            // 64 + 4 pad: transposed E tile stride
#define RSTRIDE 130           // reduce-array stride

// ws layout (floats):
//   [0 .. 511]     e2[k]
//   [512 .. 1023]  counts[k] (unsigned)
//   [1024 .. 2047] blockloss[1024]
__global__ void vq_prep(const float* __restrict__ emb, float* __restrict__ ws) {
    int k = threadIdx.x;
    if (k < KCODES) {
        const float* e = emb + k * CDIM;
        double s = 0.0;
#pragma unroll
        for (int c = 0; c < CDIM; ++c) s += (double)e[c] * (double)e[c];
        ws[k] = (float)s;
        ((unsigned*)ws)[KCODES + k] = 0u;
    }
}

__launch_bounds__(256)
__global__ void vq_main(const float* __restrict__ in, const float* __restrict__ emb,
                        float* __restrict__ ws, float* __restrict__ out) {
    __shared__ __align__(16) float xs[CDIM][BN];           // 32 KB
    __shared__ __align__(16) float es[2][CDIM][ESTRIDE];   // 34816 B (reused as scratch)
    __shared__ float e2s[KCODES];
    __shared__ unsigned hist[KCODES];
    __shared__ float wsum[4];
    __shared__ int wl[BN];
    __shared__ int wlc;
    __shared__ int bi_final[BN];
    __shared__ float loss_final[BN];

    const int tid = threadIdx.x;
    const int blk = blockIdx.x;
    const int n0  = blk * BN;
    const int b   = n0 >> 12;
    const int hw0 = n0 & 4095;
    const float* xbase = in + (size_t)b * CDIM * HWPIX + hw0;

    // stage X tile [c][p]
    {
        int p  = tid & 127;
        int c0 = tid >> 7;   // 0 or 1
#pragma unroll
        for (int i = 0; i < 32; ++i) {
            int c = c0 + i * 2;
            xs[c][p] = xbase[c * HWPIX + p];
        }
    }
    for (int i = tid; i < KCODES; i += 256) { e2s[i] = ws[i]; hist[i] = 0u; }
    if (tid == 0) wlc = 0;

    // stage E chunk 0 (transposed [c][k]); emb row-major [512][64] -> flat index works
#pragma unroll
    for (int j = 0; j < 16; ++j) {
        int flat = tid + 256 * j;          // 0..4095
        es[0][flat & 63][flat >> 6] = emb[flat];
    }
    __syncthreads();

    const int tp = tid >> 4;   // pixel group: 8 pixels
    const int tk = tid & 15;   // code group: 4 codes

    float b1[8], b2[8]; int i1[8];
#pragma unroll
    for (int i = 0; i < 8; ++i) { b1[i] = 1e30f; b2[i] = 1e30f; i1[i] = 0; }

    float ereg[16];
    for (int ck = 0; ck < NCHUNK; ++ck) {
        const int cur = ck & 1;
        if (ck + 1 < NCHUNK) {   // prefetch next chunk into regs (issue early)
            const float* ebase = emb + (ck + 1) * BKC * CDIM;
#pragma unroll
            for (int j = 0; j < 16; ++j) ereg[j] = ebase[tid + 256 * j];
        }

        float acc[8][4];
#pragma unroll
        for (int i = 0; i < 8; ++i)
#pragma unroll
            for (int j = 0; j < 4; ++j) acc[i][j] = 0.f;

        const float* xrow = &xs[0][tp * 8];
        const float* erow = &es[cur][0][tk * 4];
#pragma unroll 8
        for (int c = 0; c < CDIM; ++c) {
            float4 xa = *(const float4*)(xrow + c * BN);
            float4 xb = *(const float4*)(xrow + c * BN + 4);
            float4 ev = *(const float4*)(erow + c * ESTRIDE);
            float xv[8] = {xa.x, xa.y, xa.z, xa.w, xb.x, xb.y, xb.z, xb.w};
            float evv[4] = {ev.x, ev.y, ev.z, ev.w};
#pragma unroll
            for (int i = 0; i < 8; ++i)
#pragma unroll
                for (int j = 0; j < 4; ++j) acc[i][j] += xv[i] * evv[j];
        }

        const int kb = ck * BKC + tk * 4;
#pragma unroll
        for (int j = 0; j < 4; ++j) {
            float e2v = e2s[kb + j];
#pragma unroll
            for (int i = 0; i < 8; ++i) {
                float d = e2v - 2.f * acc[i][j];
                if (d < b1[i])      { b2[i] = b1[i]; b1[i] = d; i1[i] = kb + j; }
                else if (d < b2[i]) { b2[i] = d; }
            }
        }

        if (ck + 1 < NCHUNK) {
            __syncthreads();
#pragma unroll
            for (int j = 0; j < 16; ++j) {
                int flat = tid + 256 * j;
                es[1 - cur][flat & 63][flat >> 6] = ereg[j];
            }
            __syncthreads();
        }
    }
    __syncthreads();   // compute done; es becomes scratch

    float* rd1 = &es[0][0][0];              // [16][RSTRIDE]
    float* rd2 = rd1 + 16 * RSTRIDE;
    int*   ri1 = (int*)(rd1 + 32 * RSTRIDE);
    double* rdd = (double*)(rd1 + 48 * RSTRIDE + 16);  // byte off 24960, 8-aligned
    int*    rdi = (int*)(rdd + 256);

#pragma unroll
    for (int i = 0; i < 8; ++i) {
        int p = tp * 8 + i;
        rd1[tk * RSTRIDE + p] = b1[i];
        rd2[tk * RSTRIDE + p] = b2[i];
        ri1[tk * RSTRIDE + p] = i1[i];
    }
    __syncthreads();

    if (tid < BN) {
        const int p = tid;
        float x2 = 0.f;
#pragma unroll
        for (int c = 0; c < CDIM; ++c) { float xv = xs[c][p]; x2 += xv * xv; }
        float B1 = 1e30f, B2 = 1e30f; int I1 = 0;
#pragma unroll
        for (int t = 0; t < 16; ++t) {
            float d1 = rd1[t * RSTRIDE + p];
            float d2 = rd2[t * RSTRIDE + p];
            int   ii = ri1[t * RSTRIDE + p];
            if (d1 < B1) { B2 = fminf(B1, d2); B1 = d1; I1 = ii; }
            else         { B2 = fminf(B2, d1); }
        }
        bi_final[p]   = I1;
        loss_final[p] = x2 + B1;
        if (B2 - B1 <= TAU) { int w = atomicAdd(&wlc, 1); wl[w] = p; }
    }
    __syncthreads();

    // cooperative exact (fp64) re-resolution for near-ties — rare
    const int nfl = wlc;
    for (int w = 0; w < nfl; ++w) {
        const int p = wl[w];
        double bd = 1e300; int bi = 0;
#pragma unroll
        for (int kk = 0; kk < 2; ++kk) {
            int k = tid * 2 + kk;
            const float* e = emb + k * CDIM;
            double s = 0.0;
            for (int c = 0; c < CDIM; ++c) {
                double t = (double)xs[c][p] - (double)e[c];
                s += t * t;
            }
            if (s < bd) { bd = s; bi = k; }   // strict <: lowest k wins
        }
        rdd[tid] = bd; rdi[tid] = bi;
        __syncthreads();
        if (tid == 0) {
            double BD = 1e300; int BI = 0;
            for (int t = 0; t < 256; ++t)
                if (rdd[t] < BD) { BD = rdd[t]; BI = rdi[t]; }
            bi_final[p]   = BI;
            loss_final[p] = (float)BD;
        }
        __syncthreads();
    }

    if (tid < BN) {
        out[2 + n0 + tid] = (float)bi_final[tid];
        atomicAdd(&hist[bi_final[tid]], 1u);
    }
    float lv = (tid < BN) ? loss_final[tid] : 0.f;
#pragma unroll
    for (int off = 32; off > 0; off >>= 1) lv += __shfl_down(lv, off, 64);
    if ((tid & 63) == 0) wsum[tid >> 6] = lv;
    __syncthreads();   // covers wsum writes AND hist atomics
    if (tid == 0) ws[2 * KCODES + blk] = (wsum[0] + wsum[1]) + (wsum[2] + wsum[3]);

    unsigned* counts = ((unsigned*)ws) + KCODES;
    for (int i = tid; i < KCODES; i += 256) {
        unsigned v = hist[i];
        if (v) atomicAdd(&counts[i], v);
    }
}

__global__ void vq_final(const float* __restrict__ ws, float* __restrict__ out) {
    __shared__ float red[KCODES];
    int t = threadIdx.x;   // 512 threads

    red[t] = ws[2 * KCODES + t] + ws[2 * KCODES + 512 + t];
    __syncthreads();
    for (int s = 256; s > 0; s >>= 1) {
        if (t < s) red[t] += red[t + s];
        __syncthreads();
    }
    float loss_sum = red[0];
    __syncthreads();

    unsigned cnt = ((const unsigned*)ws)[KCODES + t];
    float p = (float)cnt / (float)NPIX;
    red[t] = p * logf(p + 1e-10f);
    __syncthreads();
    for (int s = 256; s > 0; s >>= 1) {
        if (t < s) red[t] += red[t + s];
        __syncthreads();
    }
    if (t == 0) {
        out[0] = COMMIT * loss_sum / (float)NPIX / (float)CDIM;
        out[1] = expf(-red[0]);
    }
}

extern "C" void kernel_launch(void* const* d_in, const int* in_sizes, int n_in,
                              void* d_out, int out_size, void* d_ws, size_t ws_size,
                              hipStream_t stream) {
    const float* in  = (const float*)d_in[0];   // [32, 64, 64, 64] f32
    const float* emb = (const float*)d_in[1];   // [512, 64] f32
    float* out = (float*)d_out;                 // [1 + 1 + 131072] f32
    float* ws  = (float*)d_ws;

    vq_prep<<<1, KCODES, 0, stream>>>(emb, ws);
    vq_main<<<NPIX / BN, 256, 0, stream>>>(in, emb, ws, out);
    vq_final<<<1, KCODES, 0, stream>>>(ws, out);
}

// Round 4
// 65.186 us; speedup vs baseline: 13.8950x; 4.1763x over previous
//
#include <hip/hip_runtime.h>
#include <math.h>

#define KCODES 512
#define CDIM   64
#define HWPIX  4096
#define NPIX   131072
#define BLKPX  256
#define COMMIT 0.25f
#define TAU    0.01f

typedef __attribute__((ext_vector_type(8))) short s16x8;   // 8 bf16 (4 VGPRs)
typedef __attribute__((ext_vector_type(4))) float f32x4;

static __device__ __forceinline__ unsigned short f2bf(float f) {   // RNE
    unsigned u = __float_as_uint(f);
    u += ((u >> 16) & 1u) + 0x7fffu;
    return (unsigned short)(u >> 16);
}
static __device__ __forceinline__ float bf2f(unsigned short h) {
    return __uint_as_float(((unsigned)h) << 16);
}

// ws: [0..511] e2 | [512..1023] counts | [1024..1535] blockloss
__global__ void vq_prep(const float* __restrict__ emb, float* __restrict__ ws) {
    int k = threadIdx.x;
    if (k < KCODES) {
        const float* e = emb + k * CDIM;
        double s = 0.0;
#pragma unroll
        for (int c = 0; c < CDIM; ++c) s += (double)e[c] * (double)e[c];
        ws[k] = (float)s;
        ((unsigned*)ws)[KCODES + k] = 0u;
    }
}

__launch_bounds__(256)
__global__ void vq_main(const float* __restrict__ in, const float* __restrict__ emb,
                        float* __restrict__ ws, float* __restrict__ out) {
    // E-frag layout (shorts): off = ((t*2+ks)*16 + code)*32 + grp*8  (t<8,ks<2,code<16,grp<4)
    __shared__ __align__(16) short ehi[8192];   // 16 KB
    __shared__ __align__(16) short elo[8192];   // 16 KB
    __shared__ __align__(16) float e2s[KCODES];
    __shared__ unsigned hist[KCODES];
    __shared__ float ls_loss[BLKPX];
    __shared__ int   ls_idx[BLKPX];
    __shared__ float ls_gap[BLKPX];
    __shared__ int wl[BLKPX];
    __shared__ int wlc;
    __shared__ double rdd[256];
    __shared__ int    rdi[256];

    const int tid  = threadIdx.x;
    const int lane = tid & 63;
    const int wv   = tid >> 6;
    const int lg   = lane >> 4;   // 0..3
    const int li   = lane & 15;
    const int blk  = blockIdx.x;
    const int n0   = blk * BLKPX;
    const int b    = n0 >> 12;
    const int hwp0 = (n0 & 4095) + wv * 64 + li;  // + g*16 per group
    const float* xb = in + (size_t)b * CDIM * HWPIX;

    for (int i = tid; i < KCODES; i += 256) { e2s[i] = ws[i]; hist[i] = 0u; }
    if (tid == 0) wlc = 0;

    // ---- x: load + split to bf16 hi/lo frags of (-2x); x2 partial per group
    float x2p[4];
    s16x8 xh[4][2], xl[4][2];
#pragma unroll
    for (int g = 0; g < 4; ++g) {
        float xr[16];
#pragma unroll
        for (int ks = 0; ks < 2; ++ks)
#pragma unroll
            for (int i = 0; i < 8; ++i)
                xr[ks * 8 + i] = xb[(ks * 32 + lg * 8 + i) * HWPIX + hwp0 + g * 16];
        float s = 0.f;
#pragma unroll
        for (int ks = 0; ks < 2; ++ks) {
            s16x8 h, l;
#pragma unroll
            for (int i = 0; i < 8; ++i) {
                float v = xr[ks * 8 + i];
                s += v * v;
                float m = -2.f * v;
                unsigned short hb = f2bf(m);
                h[i] = (short)hb;
                l[i] = (short)f2bf(m - bf2f(hb));
            }
            xh[g][ks] = h; xl[g][ks] = l;
        }
        x2p[g] = s;
    }

    float b1[4], b2[4]; int k1[4];
#pragma unroll
    for (int g = 0; g < 4; ++g) { b1[g] = 1e30f; b2[g] = 1e30f; k1[g] = 0; }

    // ---- 4 chunks of 128 codes
    for (int ch = 0; ch < 4; ++ch) {
        // stage E chunk (convert fp32 -> bf16 hi/lo, frag layout)
#pragma unroll
        for (int s4 = 0; s4 < 4; ++s4) {
            int seg  = tid + 256 * s4;   // 0..1023
            int code = seg >> 3;         // 0..127
            int cg   = seg & 7;
            const float* ep = emb + (ch * 128 + code) * CDIM + cg * 8;
            float4 fa = *(const float4*)(ep);
            float4 fb = *(const float4*)(ep + 4);
            float vv[8] = {fa.x, fa.y, fa.z, fa.w, fb.x, fb.y, fb.z, fb.w};
            s16x8 hh, ll;
#pragma unroll
            for (int i = 0; i < 8; ++i) {
                unsigned short hb = f2bf(vv[i]);
                hh[i] = (short)hb;
                ll[i] = (short)f2bf(vv[i] - bf2f(hb));
            }
            int off = (((code >> 4) * 2 + (cg >> 2)) * 16 + (code & 15)) * 32 + (cg & 3) * 8;
            *(s16x8*)&ehi[off] = hh;
            *(s16x8*)&elo[off] = ll;
        }
        __syncthreads();

#pragma unroll 2
        for (int t = 0; t < 8; ++t) {
            const int kb = ch * 128 + t * 16 + lg * 4;
            f32x4 e2v = *(f32x4*)&e2s[kb];
            const int ab = (t * 2) * 512 + li * 32 + lg * 8;
            s16x8 ah0 = *(s16x8*)&ehi[ab];
            s16x8 ah1 = *(s16x8*)&ehi[ab + 512];
            s16x8 al0 = *(s16x8*)&elo[ab];
            s16x8 al1 = *(s16x8*)&elo[ab + 512];
#pragma unroll
            for (int g = 0; g < 4; ++g) {
                f32x4 acc = e2v;   // acc = e2 + (-2x).e  => distance (minus x2)
                acc = __builtin_amdgcn_mfma_f32_16x16x32_bf16(ah0, xh[g][0], acc, 0, 0, 0);
                acc = __builtin_amdgcn_mfma_f32_16x16x32_bf16(ah1, xh[g][1], acc, 0, 0, 0);
                acc = __builtin_amdgcn_mfma_f32_16x16x32_bf16(ah0, xl[g][0], acc, 0, 0, 0);
                acc = __builtin_amdgcn_mfma_f32_16x16x32_bf16(ah1, xl[g][1], acc, 0, 0, 0);
                acc = __builtin_amdgcn_mfma_f32_16x16x32_bf16(al0, xh[g][0], acc, 0, 0, 0);
                acc = __builtin_amdgcn_mfma_f32_16x16x32_bf16(al1, xh[g][1], acc, 0, 0, 0);
#pragma unroll
                for (int j = 0; j < 4; ++j) {
                    float d = acc[j];
                    int k = kb + j;
                    float nb2 = fminf(fmaxf(d, b1[g]), b2[g]);
                    bool take = d < b1[g];
                    b1[g] = take ? d : b1[g];
                    k1[g] = take ? k : k1[g];
                    b2[g] = nb2;
                }
            }
        }
        __syncthreads();
    }

    // ---- reduce across lane groups (pixels live at lane&15)
#pragma unroll
    for (int g = 0; g < 4; ++g) {
#pragma unroll
        for (int m = 16; m <= 32; m <<= 1) {
            float ob1 = __shfl_xor(b1[g], m, 64);
            float ob2 = __shfl_xor(b2[g], m, 64);
            int   ok1 = __shfl_xor(k1[g], m, 64);
            float nb2 = fminf(fminf(b2[g], ob2), fmaxf(b1[g], ob1));
            bool take = (ob1 < b1[g]) || (ob1 == b1[g] && ok1 < k1[g]);
            b1[g] = take ? ob1 : b1[g];
            k1[g] = take ? ok1 : k1[g];
            b2[g] = nb2;
            x2p[g] += __shfl_xor(x2p[g], m, 64);
        }
    }

    if (lane < 16) {
#pragma unroll
        for (int g = 0; g < 4; ++g) {
            int p = wv * 64 + g * 16 + lane;
            ls_idx[p]  = k1[g];
            ls_loss[p] = x2p[g] + b1[g];
            ls_gap[p]  = b2[g] - b1[g];
        }
    }
    __syncthreads();

    if (tid < BLKPX && ls_gap[tid] <= TAU) { int w = atomicAdd(&wlc, 1); wl[w] = tid; }
    __syncthreads();

    // ---- exact fp64 re-resolution of near-ties (rare)
    const int nfl = wlc;
    for (int w = 0; w < nfl; ++w) {
        const int p   = wl[w];
        const int hwp = (n0 & 4095) + p;
        double bd = 1e300; int bi = 0;
#pragma unroll
        for (int kk = 0; kk < 2; ++kk) {
            int k = tid * 2 + kk;
            const float* e = emb + k * CDIM;
            double s = 0.0;
            for (int c = 0; c < CDIM; ++c) {
                double t = (double)xb[c * HWPIX + hwp] - (double)e[c];
                s += t * t;
            }
            if (s < bd) { bd = s; bi = k; }   // strict <: lowest k wins
        }
        rdd[tid] = bd; rdi[tid] = bi;
        __syncthreads();
        for (int s = 128; s > 0; s >>= 1) {
            if (tid < s) {
                double od = rdd[tid + s]; int oi = rdi[tid + s];
                if (od < rdd[tid] || (od == rdd[tid] && oi < rdi[tid])) { rdd[tid] = od; rdi[tid] = oi; }
            }
            __syncthreads();
        }
        if (tid == 0) { ls_idx[p] = rdi[0]; ls_loss[p] = (float)rdd[0]; }
        __syncthreads();
    }

    // ---- outputs
    if (tid < BLKPX) {
        int k = ls_idx[tid];
        out[2 + n0 + tid] = (float)k;
        atomicAdd(&hist[k], 1u);
    }
    __syncthreads();
    for (int s = 128; s > 0; s >>= 1) {          // deterministic block loss sum
        if (tid < s) ls_loss[tid] += ls_loss[tid + s];
        __syncthreads();
    }
    if (tid == 0) ws[2 * KCODES + blk] = ls_loss[0];

    unsigned* counts = ((unsigned*)ws) + KCODES;
    for (int i = tid; i < KCODES; i += 256) {
        unsigned v = hist[i];
        if (v) atomicAdd(&counts[i], v);
    }
}

__global__ void vq_final(const float* __restrict__ ws, float* __restrict__ out) {
    __shared__ float red[KCODES];
    int t = threadIdx.x;   // 512 threads

    red[t] = ws[2 * KCODES + t];
    __syncthreads();
    for (int s = 256; s > 0; s >>= 1) {
        if (t < s) red[t] += red[t + s];
        __syncthreads();
    }
    float loss_sum = red[0];
    __syncthreads();

    unsigned cnt = ((const unsigned*)ws)[KCODES + t];
    float p = (float)cnt / (float)NPIX;
    red[t] = p * logf(p + 1e-10f);
    __syncthreads();
    for (int s = 256; s > 0; s >>= 1) {
        if (t < s) red[t] += red[t + s];
        __syncthreads();
    }
    if (t == 0) {
        out[0] = COMMIT * loss_sum / ((float)NPIX * (float)CDIM);
        out[1] = expf(-red[0]);
    }
}

extern "C" void kernel_launch(void* const* d_in, const int* in_sizes, int n_in,
                              void* d_out, int out_size, void* d_ws, size_t ws_size,
                              hipStream_t stream) {
    const float* in  = (const float*)d_in[0];   // [32, 64, 64, 64] f32
    const float* emb = (const float*)d_in[1];   // [512, 64] f32
    float* out = (float*)d_out;                 // [1 + 1 + 131072] f32
    float* ws  = (float*)d_ws;

    vq_prep<<<1, KCODES, 0, stream>>>(emb, ws);
    vq_main<<<NPIX / BLKPX, 256, 0, stream>>>(in, emb, ws, out);
    vq_final<<<1, KCODES, 0, stream>>>(ws, out);
}